// Round 4
// baseline (101.792 us; speedup 1.0000x reference)
//
#include <hip/hip_runtime.h>
#include <math.h>

#define SEQ_LEN 4096
#define KSZ 128
#define OUT_LEN 3969
#define BATCH 8192
#define NBLK 256
#define NTHR 1024
#define NWAVE 16

// Single fused dispatch, last-block-done reduction (hipCUB pattern).
// 256 blocks x 1024 threads = 1 block/CU, 16 waves. One wave = one row,
// 2 rows per wave, no barriers in the row loop (verified R2 row body).
// Each block writes one coalesced 1KB partial row; threadfence + atomicAdd;
// the 256th-arriving block sums the 256x256 partial matrix (coalesced),
// does the 127-step prefix/suffix scan, and writes the 129 outputs.
// Counter is NOT reset: each launch adds exactly 256, and any 256
// consecutive integers contain exactly one == 255 (mod 256), so exactly
// one block takes the final path per launch, for any initial value.
__global__ __launch_bounds__(NTHR, 4) void conv1d_train_fused(
    const float* __restrict__ x, const float* __restrict__ y,
    const float* __restrict__ kern, const float* __restrict__ bias,
    float* __restrict__ partial, unsigned* __restrict__ counter,
    float* __restrict__ out)
{
    __shared__ float kk[KSZ];
    __shared__ float P[KSZ];        // inclusive prefix sums of kernel
    __shared__ float sl[NWAVE][256];
    __shared__ float colsum[256];
    __shared__ unsigned lastFlag;

    const int tid  = threadIdx.x;
    const int wave = tid >> 6;
    const int lane = tid & 63;

    if (tid < KSZ) kk[tid] = kern[tid];
    __syncthreads();
    if (tid < KSZ) {
        float s = 0.f;
        for (int j = 0; j <= tid; ++j) s += kk[j];   // LDS broadcast reads
        P[tid] = s;
    }
    __syncthreads();
    const float ksum = P[KSZ - 1];
    const float bs   = bias[0];

    // Per-lane edge-correction weights (verified R2).
    // head lane l<32: elems j=4l..4l+3, weight P[j]-ksum  (j=127 -> 0)
    // tail lane l>=32: elem 3968+4(l-32)+q, m=elem-3969, weight -P[m]; m=-1 -> 0
    float w0, w1, w2, w3;
    if (lane < 32) {
        const int j = 4 * lane;
        w0 = P[j] - ksum; w1 = P[j + 1] - ksum;
        w2 = P[j + 2] - ksum; w3 = P[j + 3] - ksum;
    } else {
        const int m = 4 * (lane - 32) - 1;
        w0 = (m >= 0) ? -P[m] : 0.f;
        w1 = -P[m + 1]; w2 = -P[m + 2]; w3 = -P[m + 3];
    }

    float g0 = 0.f, g1 = 0.f, g2 = 0.f, g3 = 0.f;
    float C0 = 0.f, db = 0.f;

    const int wg = blockIdx.x * NWAVE + wave;        // 0..4095

    for (int b = wg; b < BATCH; b += NBLK * NWAVE) {
        const float4* xr = reinterpret_cast<const float4*>(x + (size_t)b * SEQ_LEN);
        float4 r[16];
#pragma unroll
        for (int i = 0; i < 16; ++i) r[i] = xr[i * 64 + lane];
        const float yv = y[b];

        float tot = 0.f;
#pragma unroll
        for (int i = 0; i < 16; ++i) tot += (r[i].x + r[i].y) + (r[i].z + r[i].w);

        const float4 e = (lane < 32) ? r[0] : r[15];
        float corr = ((w0 * e.x + w1 * e.y) + (w2 * e.z + w3 * e.w));

        float t = tot, c = corr;
#pragma unroll
        for (int off = 1; off < 64; off <<= 1) {
            t += __shfl_xor(t, off, 64);
            c += __shfl_xor(c, off, 64);
        }
        // all lanes hold identical t, c
        const float logits = (ksum * t + c) * (1.f / (float)OUT_LEN) + bs;
        const float sig    = 1.f / (1.f + __expf(-logits));
        const float dconv  = (sig - yv) * (1.f / (float)OUT_LEN);

        g0 += dconv * e.x; g1 += dconv * e.y;
        g2 += dconv * e.z; g3 += dconv * e.w;
        C0 += dconv * t;   db += dconv;
    }

    // Per-wave writeout: [0..126]=G, [127]=C0, [128..254]=H, [255]=db
    if (lane < 32) {
        const int j = 4 * lane;
        sl[wave][j]     = g0;
        sl[wave][j + 1] = g1;
        sl[wave][j + 2] = g2;
        if (j + 3 < 127) sl[wave][j + 3] = g3;   // skip unused G[127]
    } else {
        const int s0 = 4 * lane - 1;             // slot = 128 + m
        if (lane > 32) sl[wave][s0] = g0;        // lane 32 q=0 -> m=-1, skip
        sl[wave][s0 + 1] = g1;
        sl[wave][s0 + 2] = g2;
        sl[wave][s0 + 3] = g3;                   // lane 63 -> slot 254
    }
    if (lane == 0) { sl[wave][127] = C0; sl[wave][255] = db; }
    __syncthreads();

    if (tid < 256) {
        float s = 0.f;
#pragma unroll
        for (int w = 0; w < NWAVE; ++w) s += sl[w][tid];
        partial[blockIdx.x * 256 + tid] = s;     // coalesced 1KB per block
    }

    // release partials, then count arrivals
    __threadfence();
    __syncthreads();
    if (tid == 0) {
        const unsigned old = atomicAdd(counter, 1u);
        lastFlag = ((old & 255u) == 255u) ? 1u : 0u;
    }
    __syncthreads();
    if (!lastFlag) return;

    // ---- last block: final reduction + scan + output ----
    __threadfence();                             // acquire side
    const int col   = tid & 255;
    const int slice = tid >> 8;                  // 0..3, 64 rows each
    float a = 0.f;
#pragma unroll 8
    for (int j = slice * 64; j < slice * 64 + 64; ++j)
        a += partial[j * 256 + col];             // coalesced per j
    sl[slice][col] = a;
    __syncthreads();
    if (tid < 256)
        colsum[tid] = (sl[0][tid] + sl[1][tid]) + (sl[2][tid] + sl[3][tid]);
    __syncthreads();

    if (tid < 128) {
        const float C0a = colsum[127];
        float pre = 0.f, suf = 0.f;
        for (int j = 0; j < 127; ++j) {
            const float g = colsum[j];           // broadcast
            const float h = colsum[128 + j];
            if (j < tid)  pre += g;
            if (j >= tid) suf += h;
        }
        const float dk = (C0a - pre - suf) * (1.f / (float)BATCH);
        out[tid] = kern[tid] - dk;
    }
    if (tid == 0) {
        const float dbo = colsum[255] * ((float)OUT_LEN / (float)BATCH);
        out[128] = bias[0] - dbo;
    }
}

extern "C" void kernel_launch(void* const* d_in, const int* in_sizes, int n_in,
                              void* d_out, int out_size, void* d_ws, size_t ws_size,
                              hipStream_t stream) {
    (void)in_sizes; (void)n_in; (void)out_size; (void)ws_size;
    const float* x    = (const float*)d_in[0];
    const float* y    = (const float*)d_in[1];
    const float* kern = (const float*)d_in[2];
    const float* bias = (const float*)d_in[3];
    float* out = (float*)d_out;

    // ws layout: partial[256*256] floats, then counter (4B).
    float*    partial = (float*)d_ws;
    unsigned* counter = (unsigned*)((char*)d_ws + (size_t)NBLK * 256 * sizeof(float));

    hipLaunchKernelGGL(conv1d_train_fused, dim3(NBLK), dim3(NTHR), 0, stream,
                       x, y, kern, bias, partial, counter, out);
}

// Round 5
// 40.160 us; speedup vs baseline: 2.5347x; 2.5347x over previous
//
#include <hip/hip_runtime.h>
#include <math.h>

#define SEQ_LEN 4096
#define KSZ 128
#define OUT_LEN 3969
#define BATCH 8192
#define NB 1024          // main grid blocks
#define NB2 16           // colreduce blocks

// Main pass (R3-proven loop body): one wave = one row, 2 rows/wave, no
// barriers in the row loop. 16 float4 loads in flight (r[16], VGPR cap 128
// via launch_bounds(256,4)), XOR-butterfly reduce, redundant sigmoid on all
// lanes, per-lane edge-gradient FMAs in registers.
// Changes vs R3: parallel prefix scan (Hillis-Steele, 7 steps) instead of
// the serial 128-step chain; partial store row-major COALESCED (1KB/block).
__global__ __launch_bounds__(256, 4) void conv1d_train_main(
    const float* __restrict__ x, const float* __restrict__ y,
    const float* __restrict__ kern, const float* __restrict__ bias,
    float* __restrict__ partial)
{
    __shared__ float P[KSZ];      // inclusive prefix sums of kernel
    __shared__ float sl[4][256];  // per-wave partials for block combine

    const int tid  = threadIdx.x;
    const int wave = tid >> 6;
    const int lane = tid & 63;

    if (tid < KSZ) P[tid] = kern[tid];
    __syncthreads();
#pragma unroll
    for (int off = 1; off < KSZ; off <<= 1) {   // Hillis-Steele scan
        float v = 0.f;
        if (tid < KSZ) {
            v = P[tid];
            if (tid >= off) v += P[tid - off];
        }
        __syncthreads();
        if (tid < KSZ) P[tid] = v;
        __syncthreads();
    }
    const float ksum = P[KSZ - 1];
    const float bs   = bias[0];

    // Per-lane edge-correction weights.
    // head lane l<32: elems j=4l..4l+3, weight P[j]-ksum  (j=127 -> 0)
    // tail lane l>=32: elem 3968+4(l-32)+q, m=elem-3969, weight -P[m]; m=-1 -> 0
    float w0, w1, w2, w3;
    if (lane < 32) {
        const int j = 4 * lane;
        w0 = P[j] - ksum; w1 = P[j + 1] - ksum;
        w2 = P[j + 2] - ksum; w3 = P[j + 3] - ksum;
    } else {
        const int m = 4 * (lane - 32) - 1;
        w0 = (m >= 0) ? -P[m] : 0.f;
        w1 = -P[m + 1]; w2 = -P[m + 2]; w3 = -P[m + 3];
    }

    float g0 = 0.f, g1 = 0.f, g2 = 0.f, g3 = 0.f;  // dconv-weighted edge accum
    float C0 = 0.f, db = 0.f;

    const int wg = blockIdx.x * 4 + wave;

    for (int b = wg; b < BATCH; b += NB * 4) {
        const float4* xr = reinterpret_cast<const float4*>(x + (size_t)b * SEQ_LEN);
        float4 r[16];
#pragma unroll
        for (int i = 0; i < 16; ++i) r[i] = xr[i * 64 + lane];
        const float yv = y[b];                       // broadcast load

        float tot = 0.f;
#pragma unroll
        for (int i = 0; i < 16; ++i) tot += (r[i].x + r[i].y) + (r[i].z + r[i].w);

        const float4 e = (lane < 32) ? r[0] : r[15];
        float corr = ((w0 * e.x + w1 * e.y) + (w2 * e.z + w3 * e.w));

        float t = tot, c = corr;
#pragma unroll
        for (int off = 1; off < 64; off <<= 1) {
            t += __shfl_xor(t, off, 64);
            c += __shfl_xor(c, off, 64);
        }
        // all lanes now hold identical t, c
        const float logits = (ksum * t + c) * (1.f / (float)OUT_LEN) + bs;
        const float sig    = 1.f / (1.f + expf(-logits));
        const float dconv  = (sig - yv) * (1.f / (float)OUT_LEN);

        g0 += dconv * e.x; g1 += dconv * e.y;
        g2 += dconv * e.z; g3 += dconv * e.w;
        C0 += dconv * t;   db += dconv;
    }

    // Per-wave writeout to LDS: [0..126]=G, [127]=C0, [128..254]=H, [255]=db
    if (lane < 32) {
        const int j = 4 * lane;
        sl[wave][j]     = g0;
        sl[wave][j + 1] = g1;
        sl[wave][j + 2] = g2;
        if (j + 3 < 127) sl[wave][j + 3] = g3;   // skip unused G[127]
    } else {
        const int s0 = 4 * lane - 1;             // slot = 128 + m
        if (lane > 32) sl[wave][s0] = g0;        // lane 32 q=0 -> m=-1, skip
        sl[wave][s0 + 1] = g1;
        sl[wave][s0 + 2] = g2;
        sl[wave][s0 + 3] = g3;                   // lane 63 -> slot 254
    }
    if (lane == 0) { sl[wave][127] = C0; sl[wave][255] = db; }
    __syncthreads();
    if (tid < 256) {
        const float s = (sl[0][tid] + sl[1][tid]) + (sl[2][tid] + sl[3][tid]);
        partial[(size_t)blockIdx.x * 256 + tid] = s;   // coalesced 1KB/block
    }
}

// Stage 2: 16 blocks x 1024 threads stream the 1024x256 partial matrix
// fully coalesced. Block g sums rows g*64..g*64+63 (4 rows x 256 cols per
// iteration, 16 iterations) -> partial2[g][256].
__global__ __launch_bounds__(1024) void conv1d_train_colreduce(
    const float* __restrict__ partial, float* __restrict__ partial2)
{
    const int col  = threadIdx.x & 255;
    const int rsub = threadIdx.x >> 8;          // 0..3
    const int base = blockIdx.x * 64;

    float a = 0.f;
#pragma unroll
    for (int j = 0; j < 16; ++j)
        a += partial[(size_t)(base + j * 4 + rsub) * 256 + col];  // coalesced 4KB/iter

    __shared__ float sl[4][256];
    sl[rsub][col] = a;
    __syncthreads();
    if (threadIdx.x < 256) {
        const int t = threadIdx.x;
        partial2[(size_t)blockIdx.x * 256 + t] =
            (sl[0][t] + sl[1][t]) + (sl[2][t] + sl[3][t]);
    }
}

// Stage 3: one block. Sum the 16x256 second-level partials, then the
// one-time 127-step prefix/suffix scan, write kernel_new (128) + bias_new.
__global__ __launch_bounds__(256) void conv1d_train_finalize(
    const float* __restrict__ partial2,
    const float* __restrict__ kern, const float* __restrict__ bias,
    float* __restrict__ out)
{
    __shared__ float colsum[256];
    const int tid = threadIdx.x;

    float a = 0.f;
#pragma unroll
    for (int g = 0; g < NB2; ++g) a += partial2[(size_t)g * 256 + tid];
    colsum[tid] = a;
    __syncthreads();

    if (tid < 128) {
        const float C0 = colsum[127];
        float pre = 0.f, suf = 0.f;
        for (int j = 0; j < 127; ++j) {
            const float g = colsum[j];           // broadcast
            const float h = colsum[128 + j];
            if (j < tid)  pre += g;
            if (j >= tid) suf += h;
        }
        const float dk = (C0 - pre - suf) * (1.f / (float)BATCH);
        out[tid] = kern[tid] - dk;
    }
    if (tid == 0) {
        const float db = colsum[255] * ((float)OUT_LEN / (float)BATCH);
        out[128] = bias[0] - db;
    }
}

extern "C" void kernel_launch(void* const* d_in, const int* in_sizes, int n_in,
                              void* d_out, int out_size, void* d_ws, size_t ws_size,
                              hipStream_t stream) {
    (void)in_sizes; (void)n_in; (void)out_size; (void)ws_size;
    const float* x    = (const float*)d_in[0];
    const float* y    = (const float*)d_in[1];
    const float* kern = (const float*)d_in[2];
    const float* bias = (const float*)d_in[3];
    float* out = (float*)d_out;

    // ws layout: partial[NB*256] floats, then partial2[NB2*256] floats.
    float* partial  = (float*)d_ws;
    float* partial2 = partial + (size_t)NB * 256;

    hipLaunchKernelGGL(conv1d_train_main, dim3(NB), dim3(256), 0, stream,
                       x, y, kern, bias, partial);
    hipLaunchKernelGGL(conv1d_train_colreduce, dim3(NB2), dim3(1024), 0, stream,
                       partial, partial2);
    hipLaunchKernelGGL(conv1d_train_finalize, dim3(1), dim3(256), 0, stream,
                       partial2, kern, bias, out);
}